// Round 14
// baseline (2904.705 us; speedup 1.0000x reference)
//
#include <hip/hip_runtime.h>

// Kernel ridge regression, RBF kernel. N=M=8192, D=32, gamma=1/32, reg=1e-3.
// R14 = R13 (single-barrier Chronopoulos-Gear CG, block-local LDS vectors,
// fence-free relaxed agent-scope atomics) +
//  - NITER 128->112: measured convergence slope (err(80)=0.0703,
//    err(128)=0.0234 -> ln-slope -0.023/iter) gives err(112)~0.034,
//    1.9x under threshold. First data-driven cut (R5 lesson: never cut blind).
//  - post-barrier reorder: w-gather loads issued into registers BEFORE the
//    wave-0 scalar recurrence, overlapping L3 latency with the slot reduce
//    (R13 serialized them across the broadcast sync).
//  - rho partials distributed over all 256 blocks (32 distinct rows each);
//    R13's slice-0-only rho added skew that gated the global barrier.

#define NN 8192
#define DD 32
#define REGL 1e-3f
#define NITER 112
#define NBLK 256
#define NC2 (-0.045084220027780106f)  // -gamma*log2e
#define SCF (0.3002806023f)           // sqrt(2*gamma*log2e)

typedef short v8s __attribute__((ext_vector_type(8)));
typedef float v4f __attribute__((ext_vector_type(4)));

__device__ __forceinline__ float fast_exp2(float x) {
#if __has_builtin(__builtin_amdgcn_exp2f)
  return __builtin_amdgcn_exp2f(x);
#else
  float r;
  asm("v_exp_f32 %0, %1" : "=v"(r) : "v"(x));
  return r;
#endif
}

// ---- relaxed agent-scope coherent accessors ----
__device__ __forceinline__ float ld_f(const float* p) {
  return __hip_atomic_load(p, __ATOMIC_RELAXED, __HIP_MEMORY_SCOPE_AGENT);
}
__device__ __forceinline__ void st_f(float* p, float v) {
  __hip_atomic_store(p, v, __ATOMIC_RELAXED, __HIP_MEMORY_SCOPE_AGENT);
}
__device__ __forceinline__ double ld_d(const double* p) {
  return __hip_atomic_load(p, __ATOMIC_RELAXED, __HIP_MEMORY_SCOPE_AGENT);
}
__device__ __forceinline__ void add_d(double* p, double v) {
  __hip_atomic_fetch_add(p, v, __ATOMIC_RELAXED, __HIP_MEMORY_SCOPE_AGENT);
}

__device__ __forceinline__ ushort f2bf(float x) {  // RNE float->bf16 bits
  unsigned u = __float_as_uint(x);
  return (ushort)((u + 0x7fff + ((u >> 16) & 1)) >> 16);
}
__device__ __forceinline__ float bf2f(ushort b) {
  return __uint_as_float(((unsigned)b) << 16);
}

__device__ __forceinline__ double bfly64_d(double v) {
#pragma unroll
  for (int m = 1; m < 64; m <<= 1) v += __shfl_xor(v, m, 64);
  return v;
}
__device__ __forceinline__ double bfly32_d(double v) {
#pragma unroll
  for (int m = 1; m < 32; m <<= 1) v += __shfl_xor(v, m, 64);
  return v;
}
__device__ __forceinline__ double wave_down_sum_d(double v) {
#pragma unroll
  for (int off = 32; off > 0; off >>= 1) v += __shfl_down(v, off, 64);
  return v;
}

// ---- fence-free hierarchical global barrier (validated R11-R13) ----
__device__ __forceinline__ void gbarrier(unsigned* bar) {
  __builtin_amdgcn_s_waitcnt(0);
  __syncthreads();
  if (threadIdx.x == 0) {
    unsigned* gen = bar + 272;
    unsigned g =
        __hip_atomic_load(gen, __ATOMIC_RELAXED, __HIP_MEMORY_SCOPE_AGENT);
    unsigned a = __hip_atomic_fetch_add(&bar[(blockIdx.x >> 4) * 16], 1u,
                                        __ATOMIC_RELAXED,
                                        __HIP_MEMORY_SCOPE_AGENT);
    bool pub = false;
    if (a == 15u) {
      unsigned ra = __hip_atomic_fetch_add(bar + 256, 1u, __ATOMIC_RELAXED,
                                           __HIP_MEMORY_SCOPE_AGENT);
      if (ra == 15u) {
#pragma unroll
        for (int k = 0; k < 16; ++k)
          __hip_atomic_store(&bar[k * 16], 0u, __ATOMIC_RELAXED,
                             __HIP_MEMORY_SCOPE_AGENT);
        __hip_atomic_store(bar + 256, 0u, __ATOMIC_RELAXED,
                           __HIP_MEMORY_SCOPE_AGENT);
        __builtin_amdgcn_s_waitcnt(0);
        __hip_atomic_store(gen, g + 1u, __ATOMIC_RELAXED,
                           __HIP_MEMORY_SCOPE_AGENT);
        pub = true;
      }
    }
    if (!pub) {
      unsigned t = 0;
      while (__hip_atomic_load(gen, __ATOMIC_RELAXED,
                               __HIP_MEMORY_SCOPE_AGENT) == g) {
        if (t < 64)
          __builtin_amdgcn_s_sleep(1);
        else
          __builtin_amdgcn_s_sleep(8);
        if (++t > (1u << 20)) break;  // escape hatch: fail, don't hang
      }
    }
  }
  __atomic_signal_fence(__ATOMIC_SEQ_CST);
  __syncthreads();
}

// hi/lo bf16 fragment from global X: lane holds row `row`, k = kb..kb+7.
__device__ __forceinline__ void conv_frag(const float* __restrict__ X, int row,
                                          int kb, v8s& h, v8s& l) {
  const float4* rp = (const float4*)(X + (size_t)row * DD + kb);
  float4 f0 = rp[0], f1 = rp[1];
  float f[8] = {f0.x, f0.y, f0.z, f0.w, f1.x, f1.y, f1.z, f1.w};
  union {
    v8s v;
    ushort u[8];
  } H, L;
#pragma unroll
  for (int j = 0; j < 8; ++j) {
    float fs = SCF * f[j];
    ushort hb = f2bf(fs);
    H.u[j] = hb;
    L.u[j] = f2bf(fs - bf2f(hb));
  }
  h = H.v;
  l = L.v;
}

// ---------------- setup kernels ----------------

__global__ void setup_zero(double* __restrict__ slots, int nsl,
                           unsigned* __restrict__ bar) {
  int i = blockIdx.x * 256 + threadIdx.x;
  int st = gridDim.x * 256;
  for (int k = i; k < nsl; k += st) slots[k] = 0.0;
  if (i < 512) bar[i] = 0u;
}

// stores NC2 * ||x||^2
__global__ void row_norms(const float* __restrict__ X, float* __restrict__ xx) {
  int i = blockIdx.x * blockDim.x + threadIdx.x;
  if (i < NN) {
    const float4* row = (const float4*)(X + (size_t)i * DD);
    float s = 0.f;
#pragma unroll
    for (int k = 0; k < DD / 4; ++k) {
      float4 v = row[k];
      s += v.x * v.x + v.y * v.y + v.z * v.z + v.w * v.w;
    }
    xx[i] = NC2 * s;
  }
}

// ---------------- matvec compute core (4 row-tiles / wave) ----------------
__device__ __forceinline__ void mv_compute(const v8s* ah, const v8s* al,
                                           const ushort (*Bh)[512],
                                           const ushort (*Bl)[512],
                                           const float* Wj, int lane,
                                           float racc[4][4]) {
  const int n = lane & 15;
  for (int t = 0; t < 16; ++t) {
    v8s bh = *(const v8s*)&Bh[t][lane * 8];
    v8s bl = *(const v8s*)&Bl[t][lane * 8];
    float wn = Wj[t * 16 + n];
#pragma unroll
    for (int rs = 0; rs < 4; ++rs) {
      v4f c = {0.f, 0.f, 0.f, 0.f};
      c = __builtin_amdgcn_mfma_f32_16x16x32_bf16(al[rs], bh, c, 0, 0, 0);
      c = __builtin_amdgcn_mfma_f32_16x16x32_bf16(ah[rs], bl, c, 0, 0, 0);
      c = __builtin_amdgcn_mfma_f32_16x16x32_bf16(ah[rs], bh, c, 0, 0, 0);
#pragma unroll
      for (int u = 0; u < 4; ++u)
        racc[rs][u] = fmaf(fast_exp2(c[u]), wn, racc[rs][u]);
    }
  }
}

// ---------------- persistent CG-CG kernel ----------------
// Grid 256 blocks x 1024 threads: 8 rowblocks (1024 rows) x 32 slices
// (256 cols). All CG vectors live in block-local LDS.

__global__ __launch_bounds__(1024, 4) void cg_persist(
    const float* __restrict__ Xtr, const float* __restrict__ Xte,
    const float* __restrict__ xx_tr, const float* __restrict__ xx_te,
    const float* __restrict__ y, float* __restrict__ qp0,
    float* __restrict__ qp1, double* __restrict__ rho_s,
    double* __restrict__ mu_s, unsigned* __restrict__ bar,
    float* __restrict__ out, int db) {
  __shared__ __align__(16) ushort Bh[16][512];
  __shared__ __align__(16) ushort Bl[16][512];
  __shared__ float Wj[256];
  __shared__ float Ebj[256];
  __shared__ float Erow[1024];
  __shared__ float Rrow[1024], Qrow[1024];
  __shared__ float Rcol[256], Qcol[256], Pcol[256], Xcol[256];
  __shared__ double sredq[16];
  __shared__ float s_ab[2];  // alpha, beta

  const int tid = threadIdx.x;
  const int lane = tid & 63;
  const int wid = tid >> 6;
  const int n = lane & 15, q4 = lane >> 4;
  const int rbi = blockIdx.x & 7;
  const int sli = blockIdx.x >> 3;
  const int rowbase = rbi * 1024;
  const int i0 = rowbase + wid * 64;
  const int jbase = sli * 256;

  // ---- stage B-slice into LDS once ----
  {
    int c = tid & 255;
    int j = jbase + c;
    int g = tid >> 8;
    int tile = c >> 4, cl = c & 15;
    const float4* rp = (const float4*)(Xtr + (size_t)j * DD);
    float4 f0 = rp[2 * g], f1 = rp[2 * g + 1];
    float f[8] = {f0.x, f0.y, f0.z, f0.w, f1.x, f1.y, f1.z, f1.w};
    union {
      ushort u[8];
      uint4 qq;
    } H, L;
#pragma unroll
    for (int e = 0; e < 8; ++e) {
      float fs = SCF * f[e];
      ushort hb = f2bf(fs);
      H.u[e] = hb;
      L.u[e] = f2bf(fs - bf2f(hb));
    }
    int ln = cl + 16 * g;
    *(uint4*)&Bh[tile][ln * 8] = H.qq;
    *(uint4*)&Bl[tile][ln * 8] = L.qq;
  }
  if (tid < 256) Ebj[tid] = fast_exp2(xx_tr[jbase + tid]);
  Erow[tid] = fast_exp2(xx_tr[rowbase + tid]);

  // ---- block-local CG state ----
  Rrow[tid] = y[rowbase + tid];
  Qrow[tid] = 0.f;
  if (tid < 256) {
    Rcol[tid] = y[jbase + tid];
    Qcol[tid] = 0.f;
    Pcol[tid] = 0.f;
    Xcol[tid] = 0.f;
  }

  // ---- A fragments in registers, converted once ----
  v8s ah[4], al[4];
#pragma unroll
  for (int rs = 0; rs < 4; ++rs)
    conv_frag(Xtr, i0 + rs * 16 + n, q4 * 8, ah[rs], al[rs]);

  double rho_old = 1.0, alpha_old = 1.0;  // wave-0 recurrence state
  __syncthreads();

  for (int it = 0; it < NITER; ++it) {
    float* qp = (db && (it & 1)) ? qp1 : qp0;

    // 1. matvec input: Wj = r_k[cols] * col exp factor (same-thread Rcol)
    if (tid < 256) Wj[tid] = Rcol[tid] * Ebj[tid];
    __syncthreads();  // Wj ready; also orders prev-iter Rrow writes below

    // 2. rho partial, distributed: this block sums 32 distinct rows
    //    (rows rowbase + sli*32 + [0,32)); 256 blocks cover all 8192 once.
    if (tid < 32) {
      float rvv = Rrow[sli * 32 + tid];
      double acc = bfly32_d((double)rvv * (double)rvv);
      if (tid == 0) add_d(&rho_s[(size_t)it * 32 + (blockIdx.x & 31)], acc);
    }

    // 3. matvec on r
    float racc[4][4] = {};
    mv_compute(ah, al, Bh, Bl, Wj, lane, racc);
#pragma unroll
    for (int rs = 0; rs < 4; ++rs)
#pragma unroll
      for (int u = 0; u < 4; ++u) {
#pragma unroll
        for (int m = 1; m < 16; m <<= 1)
          racc[rs][u] += __shfl_xor(racc[rs][u], m, 64);
      }
    double cmu = 0.0;
    if (n == 0) {
#pragma unroll
      for (int rs = 0; rs < 4; ++rs)
#pragma unroll
        for (int u = 0; u < 4; ++u) {
          int lrow = wid * 64 + rs * 16 + q4 * 4 + u;
          float qc = racc[rs][u] * Erow[lrow];  // (K r)_row, this slice
          st_f(&qp[(size_t)sli * NN + rowbase + lrow], qc);
          cmu += (double)qc * (double)Rrow[lrow];  // r.Kr partial
        }
    }
    cmu = bfly64_d(cmu);
    if (lane == 0) sredq[wid] = cmu;
    __syncthreads();
    if (tid == 0) {
      double t = 0.0;
#pragma unroll
      for (int k3 = 0; k3 < 16; ++k3) t += sredq[k3];
      add_d(&mu_s[(size_t)it * 32 + (blockIdx.x & 31)], t);
    }

    gbarrier(bar);  // the ONE barrier: qp + rho + mu complete

    // 4. w-gathers FIRST (independent of alpha/beta): issue all L3 loads
    //    into registers so their latency overlaps the scalar phase.
    float gr[32];
    {
      const float* qb = qp + rowbase + tid;
#pragma unroll
      for (int s2 = 0; s2 < 32; ++s2) gr[s2] = ld_f(qb + (size_t)s2 * NN);
    }
    float wc = 0.f;
    if (tid < 256) {
      const float* qb = qp + jbase + tid;
#pragma unroll
      for (int s2 = 0; s2 < 32; ++s2) wc += ld_f(qb + (size_t)s2 * NN);
      wc = fmaf(REGL, Rcol[tid], wc);
    }

    // 5. scalars via CG-CG recurrence (wave 0), overlapped with gathers
    if (wid == 0) {
      double r1 = bfly32_d(ld_d(rho_s + (size_t)it * 32 + (lane & 31)));
      double m1 = bfly32_d(ld_d(mu_s + (size_t)it * 32 + (lane & 31)));
      double mu = m1 + (double)REGL * r1;  // r.(K+reg I)r
      double beta_d = (it == 0) ? 0.0 : r1 / rho_old;
      double alpha_d =
          (it == 0) ? r1 / mu : r1 / (mu - r1 * beta_d / alpha_old);
      rho_old = r1;
      alpha_old = alpha_d;
      if (lane == 0) {
        s_ab[0] = (float)alpha_d;
        s_ab[1] = (float)beta_d;
      }
    }
    float wr = 0.f;
#pragma unroll
    for (int s2 = 0; s2 < 32; ++s2) wr += gr[s2];
    wr = fmaf(REGL, Rrow[tid], wr);
    __syncthreads();
    const float alpha = s_ab[0], beta = s_ab[1];

    // 6. block-local updates: q = w + beta q; p = r + beta p;
    //    x += alpha p; r -= alpha q.
    {
      float qn = fmaf(beta, Qrow[tid], wr);
      Qrow[tid] = qn;
      Rrow[tid] = fmaf(-alpha, qn, Rrow[tid]);
    }
    if (tid < 256) {
      float qn = fmaf(beta, Qcol[tid], wc);
      Qcol[tid] = qn;
      float pn = fmaf(beta, Pcol[tid], Rcol[tid]);
      Pcol[tid] = pn;
      Xcol[tid] = fmaf(alpha, pn, Xcol[tid]);
      Rcol[tid] = fmaf(-alpha, qn, Rcol[tid]);
    }
    if (!db) gbarrier(bar);  // single-buffer: protect qp before next matvec
  }

  // ---- predict: out = K_test @ x, x = Xcol (block-local) ----
  {
    v8s th[4], tl[4];
#pragma unroll
    for (int rs = 0; rs < 4; ++rs)
      conv_frag(Xte, i0 + rs * 16 + n, q4 * 8, th[rs], tl[rs]);
    if (tid < 256) Wj[tid] = Xcol[tid] * Ebj[tid];
    Erow[tid] = fast_exp2(xx_te[rowbase + tid]);
    __syncthreads();
    float racc[4][4] = {};
    mv_compute(th, tl, Bh, Bl, Wj, lane, racc);
#pragma unroll
    for (int rs = 0; rs < 4; ++rs)
#pragma unroll
      for (int u = 0; u < 4; ++u) {
#pragma unroll
        for (int m = 1; m < 16; m <<= 1)
          racc[rs][u] += __shfl_xor(racc[rs][u], m, 64);
      }
    if (n == 0) {
#pragma unroll
      for (int rs = 0; rs < 4; ++rs)
#pragma unroll
        for (int u = 0; u < 4; ++u) {
          int lrow = wid * 64 + rs * 16 + q4 * 4 + u;
          st_f(&qp0[(size_t)sli * NN + rowbase + lrow],
               racc[rs][u] * Erow[lrow]);
        }
    }
    gbarrier(bar);
    if (sli == 0) {
      const float* qb = qp0 + rowbase + tid;
      float s = 0.f;
#pragma unroll
      for (int s2 = 0; s2 < 32; ++s2) s += ld_f(qb + (size_t)s2 * NN);
      out[rowbase + tid] = s;
    }
  }
}

// ---------------- launcher ----------------

extern "C" void kernel_launch(void* const* d_in, const int* in_sizes, int n_in,
                              void* d_out, int out_size, void* d_ws,
                              size_t ws_size, hipStream_t stream) {
  const float* X_train = (const float*)d_in[0];
  const float* y_train = (const float*)d_in[1];
  const float* X_test = (const float*)d_in[2];
  float* out = (float*)d_out;

  char* w = (char*)d_ws;
  size_t off = 0;
  float* xx_tr = (float*)(w + off); off += NN * 4;
  float* xx_te = (float*)(w + off); off += NN * 4;
  double* rho_s = (double*)(w + off); off += (size_t)NITER * 32 * 8;
  double* mu_s = (double*)(w + off); off += (size_t)NITER * 32 * 8;
  unsigned* bar = (unsigned*)(w + off); off += 2048;
  off = (off + 255) & ~(size_t)255;
  float* qp0 = (float*)(w + off); off += (size_t)32 * NN * 4;  // 1MB
  size_t need0 = off;
  float* qp1 = (float*)(w + off); off += (size_t)32 * NN * 4;  // 1MB
  size_t need1 = off;

  int db = (ws_size >= need1) ? 1 : 0;
  if (ws_size < need0) return;  // ~1.2MB; proven available (R12/R13 ran)
  if (!db) qp1 = qp0;

  const int nslots = 2 * NITER * 32;
  setup_zero<<<32, 256, 0, stream>>>(rho_s, nslots, bar);
  row_norms<<<NN / 256, 256, 0, stream>>>(X_train, xx_tr);
  row_norms<<<NN / 256, 256, 0, stream>>>(X_test, xx_te);

  cg_persist<<<NBLK, 1024, 0, stream>>>(X_train, X_test, xx_tr, xx_te,
                                        y_train, qp0, qp1, rho_s, mu_s, bar,
                                        out, db);
}

// Round 15
// 2403.618 us; speedup vs baseline: 1.2085x; 1.2085x over previous
//
#include <hip/hip_runtime.h>

// Kernel ridge regression, RBF kernel. N=M=8192, D=32, gamma=1/32, reg=1e-3.
// R15 = R13 EXACTLY (single-barrier Chronopoulos-Gear CG, block-local LDS
// vectors, fence-free relaxed agent-scope atomics) with ONLY NITER 128->112.
// R14's gather-reorder + distributed-rho regressed per-iter 21.0->25.7us
// (the 32-deep register gather burst lengthened the pre-broadcast vmcnt
// drain) — reverted. NITER=112 validated by R14: absmax 0.015625 (bf16
// floor) at 112 iters.

#define NN 8192
#define DD 32
#define REGL 1e-3f
#define NITER 112
#define NBLK 256
#define NC2 (-0.045084220027780106f)  // -gamma*log2e
#define SCF (0.3002806023f)           // sqrt(2*gamma*log2e)

typedef short v8s __attribute__((ext_vector_type(8)));
typedef float v4f __attribute__((ext_vector_type(4)));

__device__ __forceinline__ float fast_exp2(float x) {
#if __has_builtin(__builtin_amdgcn_exp2f)
  return __builtin_amdgcn_exp2f(x);
#else
  float r;
  asm("v_exp_f32 %0, %1" : "=v"(r) : "v"(x));
  return r;
#endif
}

// ---- relaxed agent-scope coherent accessors ----
__device__ __forceinline__ float ld_f(const float* p) {
  return __hip_atomic_load(p, __ATOMIC_RELAXED, __HIP_MEMORY_SCOPE_AGENT);
}
__device__ __forceinline__ void st_f(float* p, float v) {
  __hip_atomic_store(p, v, __ATOMIC_RELAXED, __HIP_MEMORY_SCOPE_AGENT);
}
__device__ __forceinline__ double ld_d(const double* p) {
  return __hip_atomic_load(p, __ATOMIC_RELAXED, __HIP_MEMORY_SCOPE_AGENT);
}
__device__ __forceinline__ void add_d(double* p, double v) {
  __hip_atomic_fetch_add(p, v, __ATOMIC_RELAXED, __HIP_MEMORY_SCOPE_AGENT);
}

__device__ __forceinline__ ushort f2bf(float x) {  // RNE float->bf16 bits
  unsigned u = __float_as_uint(x);
  return (ushort)((u + 0x7fff + ((u >> 16) & 1)) >> 16);
}
__device__ __forceinline__ float bf2f(ushort b) {
  return __uint_as_float(((unsigned)b) << 16);
}

__device__ __forceinline__ double bfly64_d(double v) {
#pragma unroll
  for (int m = 1; m < 64; m <<= 1) v += __shfl_xor(v, m, 64);
  return v;
}
__device__ __forceinline__ double bfly32_d(double v) {
#pragma unroll
  for (int m = 1; m < 32; m <<= 1) v += __shfl_xor(v, m, 64);
  return v;
}
__device__ __forceinline__ double wave_down_sum_d(double v) {
#pragma unroll
  for (int off = 32; off > 0; off >>= 1) v += __shfl_down(v, off, 64);
  return v;
}

// ---- fence-free hierarchical global barrier (validated R11-R13) ----
__device__ __forceinline__ void gbarrier(unsigned* bar) {
  __builtin_amdgcn_s_waitcnt(0);
  __syncthreads();
  if (threadIdx.x == 0) {
    unsigned* gen = bar + 272;
    unsigned g =
        __hip_atomic_load(gen, __ATOMIC_RELAXED, __HIP_MEMORY_SCOPE_AGENT);
    unsigned a = __hip_atomic_fetch_add(&bar[(blockIdx.x >> 4) * 16], 1u,
                                        __ATOMIC_RELAXED,
                                        __HIP_MEMORY_SCOPE_AGENT);
    bool pub = false;
    if (a == 15u) {
      unsigned ra = __hip_atomic_fetch_add(bar + 256, 1u, __ATOMIC_RELAXED,
                                           __HIP_MEMORY_SCOPE_AGENT);
      if (ra == 15u) {
#pragma unroll
        for (int k = 0; k < 16; ++k)
          __hip_atomic_store(&bar[k * 16], 0u, __ATOMIC_RELAXED,
                             __HIP_MEMORY_SCOPE_AGENT);
        __hip_atomic_store(bar + 256, 0u, __ATOMIC_RELAXED,
                           __HIP_MEMORY_SCOPE_AGENT);
        __builtin_amdgcn_s_waitcnt(0);
        __hip_atomic_store(gen, g + 1u, __ATOMIC_RELAXED,
                           __HIP_MEMORY_SCOPE_AGENT);
        pub = true;
      }
    }
    if (!pub) {
      unsigned t = 0;
      while (__hip_atomic_load(gen, __ATOMIC_RELAXED,
                               __HIP_MEMORY_SCOPE_AGENT) == g) {
        if (t < 64)
          __builtin_amdgcn_s_sleep(1);
        else
          __builtin_amdgcn_s_sleep(8);
        if (++t > (1u << 20)) break;  // escape hatch: fail, don't hang
      }
    }
  }
  __atomic_signal_fence(__ATOMIC_SEQ_CST);
  __syncthreads();
}

// hi/lo bf16 fragment from global X: lane holds row `row`, k = kb..kb+7.
__device__ __forceinline__ void conv_frag(const float* __restrict__ X, int row,
                                          int kb, v8s& h, v8s& l) {
  const float4* rp = (const float4*)(X + (size_t)row * DD + kb);
  float4 f0 = rp[0], f1 = rp[1];
  float f[8] = {f0.x, f0.y, f0.z, f0.w, f1.x, f1.y, f1.z, f1.w};
  union {
    v8s v;
    ushort u[8];
  } H, L;
#pragma unroll
  for (int j = 0; j < 8; ++j) {
    float fs = SCF * f[j];
    ushort hb = f2bf(fs);
    H.u[j] = hb;
    L.u[j] = f2bf(fs - bf2f(hb));
  }
  h = H.v;
  l = L.v;
}

// ---------------- setup kernels ----------------

__global__ void setup_zero(double* __restrict__ slots, int nsl,
                           unsigned* __restrict__ bar) {
  int i = blockIdx.x * 256 + threadIdx.x;
  int st = gridDim.x * 256;
  for (int k = i; k < nsl; k += st) slots[k] = 0.0;
  if (i < 512) bar[i] = 0u;
}

// stores NC2 * ||x||^2
__global__ void row_norms(const float* __restrict__ X, float* __restrict__ xx) {
  int i = blockIdx.x * blockDim.x + threadIdx.x;
  if (i < NN) {
    const float4* row = (const float4*)(X + (size_t)i * DD);
    float s = 0.f;
#pragma unroll
    for (int k = 0; k < DD / 4; ++k) {
      float4 v = row[k];
      s += v.x * v.x + v.y * v.y + v.z * v.z + v.w * v.w;
    }
    xx[i] = NC2 * s;
  }
}

// ---------------- matvec compute core (4 row-tiles / wave) ----------------
__device__ __forceinline__ void mv_compute(const v8s* ah, const v8s* al,
                                           const ushort (*Bh)[512],
                                           const ushort (*Bl)[512],
                                           const float* Wj, int lane,
                                           float racc[4][4]) {
  const int n = lane & 15;
  for (int t = 0; t < 16; ++t) {
    v8s bh = *(const v8s*)&Bh[t][lane * 8];
    v8s bl = *(const v8s*)&Bl[t][lane * 8];
    float wn = Wj[t * 16 + n];
#pragma unroll
    for (int rs = 0; rs < 4; ++rs) {
      v4f c = {0.f, 0.f, 0.f, 0.f};
      c = __builtin_amdgcn_mfma_f32_16x16x32_bf16(al[rs], bh, c, 0, 0, 0);
      c = __builtin_amdgcn_mfma_f32_16x16x32_bf16(ah[rs], bl, c, 0, 0, 0);
      c = __builtin_amdgcn_mfma_f32_16x16x32_bf16(ah[rs], bh, c, 0, 0, 0);
#pragma unroll
      for (int u = 0; u < 4; ++u)
        racc[rs][u] = fmaf(fast_exp2(c[u]), wn, racc[rs][u]);
    }
  }
}

// ---------------- persistent CG-CG kernel ----------------
// Grid 256 blocks x 1024 threads: 8 rowblocks (1024 rows) x 32 slices
// (256 cols). All CG vectors live in block-local LDS.

__global__ __launch_bounds__(1024, 4) void cg_persist(
    const float* __restrict__ Xtr, const float* __restrict__ Xte,
    const float* __restrict__ xx_tr, const float* __restrict__ xx_te,
    const float* __restrict__ y, float* __restrict__ qp0,
    float* __restrict__ qp1, double* __restrict__ rho_s,
    double* __restrict__ mu_s, unsigned* __restrict__ bar,
    float* __restrict__ out, int db) {
  __shared__ __align__(16) ushort Bh[16][512];
  __shared__ __align__(16) ushort Bl[16][512];
  __shared__ float Wj[256];
  __shared__ float Ebj[256];
  __shared__ float Erow[1024];
  __shared__ float Rrow[1024], Qrow[1024];
  __shared__ float Rcol[256], Qcol[256], Pcol[256], Xcol[256];
  __shared__ double sredq[16];
  __shared__ double sredr[16];
  __shared__ float s_ab[2];  // alpha, beta

  const int tid = threadIdx.x;
  const int lane = tid & 63;
  const int wid = tid >> 6;
  const int n = lane & 15, q4 = lane >> 4;
  const int rbi = blockIdx.x & 7;
  const int sli = blockIdx.x >> 3;
  const int rowbase = rbi * 1024;
  const int i0 = rowbase + wid * 64;
  const int jbase = sli * 256;

  // ---- stage B-slice into LDS once ----
  {
    int c = tid & 255;
    int j = jbase + c;
    int g = tid >> 8;
    int tile = c >> 4, cl = c & 15;
    const float4* rp = (const float4*)(Xtr + (size_t)j * DD);
    float4 f0 = rp[2 * g], f1 = rp[2 * g + 1];
    float f[8] = {f0.x, f0.y, f0.z, f0.w, f1.x, f1.y, f1.z, f1.w};
    union {
      ushort u[8];
      uint4 qq;
    } H, L;
#pragma unroll
    for (int e = 0; e < 8; ++e) {
      float fs = SCF * f[e];
      ushort hb = f2bf(fs);
      H.u[e] = hb;
      L.u[e] = f2bf(fs - bf2f(hb));
    }
    int ln = cl + 16 * g;
    *(uint4*)&Bh[tile][ln * 8] = H.qq;
    *(uint4*)&Bl[tile][ln * 8] = L.qq;
  }
  if (tid < 256) Ebj[tid] = fast_exp2(xx_tr[jbase + tid]);
  Erow[tid] = fast_exp2(xx_tr[rowbase + tid]);

  // ---- block-local CG state ----
  Rrow[tid] = y[rowbase + tid];
  Qrow[tid] = 0.f;
  if (tid < 256) {
    Rcol[tid] = y[jbase + tid];
    Qcol[tid] = 0.f;
    Pcol[tid] = 0.f;
    Xcol[tid] = 0.f;
  }

  // ---- A fragments in registers, converted once ----
  v8s ah[4], al[4];
#pragma unroll
  for (int rs = 0; rs < 4; ++rs)
    conv_frag(Xtr, i0 + rs * 16 + n, q4 * 8, ah[rs], al[rs]);

  double rho_old = 1.0, alpha_old = 1.0;  // wave-0 recurrence state
  __syncthreads();

  for (int it = 0; it < NITER; ++it) {
    float* qp = (db && (it & 1)) ? qp1 : qp0;

    // 1. matvec input: Wj = r_k[cols] * col exp factor
    if (tid < 256) Wj[tid] = Rcol[tid] * Ebj[tid];
    // 2. rho partial (slice-0 blocks): r.r over this rowblock
    if (sli == 0) {
      float rvv = Rrow[tid];
      double acc = wave_down_sum_d((double)rvv * (double)rvv);
      if (lane == 0) sredr[wid] = acc;
    }
    __syncthreads();
    if (sli == 0 && tid == 0) {
      double t = 0.0;
#pragma unroll
      for (int k3 = 0; k3 < 16; ++k3) t += sredr[k3];
      add_d(&rho_s[(size_t)it * 32 + rbi], t);
    }

    // 3. matvec on r
    float racc[4][4] = {};
    mv_compute(ah, al, Bh, Bl, Wj, lane, racc);
#pragma unroll
    for (int rs = 0; rs < 4; ++rs)
#pragma unroll
      for (int u = 0; u < 4; ++u) {
#pragma unroll
        for (int m = 1; m < 16; m <<= 1)
          racc[rs][u] += __shfl_xor(racc[rs][u], m, 64);
      }
    double cmu = 0.0;
    if (n == 0) {
#pragma unroll
      for (int rs = 0; rs < 4; ++rs)
#pragma unroll
        for (int u = 0; u < 4; ++u) {
          int lrow = wid * 64 + rs * 16 + q4 * 4 + u;
          float qc = racc[rs][u] * Erow[lrow];  // (K r)_row, this slice
          st_f(&qp[(size_t)sli * NN + rowbase + lrow], qc);
          cmu += (double)qc * (double)Rrow[lrow];  // r.Kr partial
        }
    }
    cmu = bfly64_d(cmu);
    if (lane == 0) sredq[wid] = cmu;
    __syncthreads();
    if (tid == 0) {
      double t = 0.0;
#pragma unroll
      for (int k3 = 0; k3 < 16; ++k3) t += sredq[k3];
      add_d(&mu_s[(size_t)it * 32 + (blockIdx.x & 31)], t);
    }

    gbarrier(bar);  // the ONE barrier: qp + rho + mu complete

    // 4. scalars via CG-CG recurrence (wave 0, then LDS broadcast)
    if (wid == 0) {
      double r1 = bfly32_d(ld_d(rho_s + (size_t)it * 32 + (lane & 31)));
      double m1 = bfly32_d(ld_d(mu_s + (size_t)it * 32 + (lane & 31)));
      double mu = m1 + (double)REGL * r1;  // r.(K+reg I)r
      double beta_d = (it == 0) ? 0.0 : r1 / rho_old;
      double alpha_d =
          (it == 0) ? r1 / mu : r1 / (mu - r1 * beta_d / alpha_old);
      rho_old = r1;
      alpha_old = alpha_d;
      if (lane == 0) {
        s_ab[0] = (float)alpha_d;
        s_ab[1] = (float)beta_d;
      }
    }
    __syncthreads();
    const float alpha = s_ab[0], beta = s_ab[1];

    // 5. gather w = K r (+reg r) at rows and cols; flat ascending slice
    //    order everywhere so replicated values stay bitwise identical.
    float wr;
    {
      const float* qb = qp + rowbase + tid;
      float s = 0.f;
#pragma unroll
      for (int s2 = 0; s2 < 32; ++s2) s += ld_f(qb + (size_t)s2 * NN);
      wr = fmaf(REGL, Rrow[tid], s);
    }
    float wc = 0.f;
    if (tid < 256) {
      const float* qb = qp + jbase + tid;
      float s = 0.f;
#pragma unroll
      for (int s2 = 0; s2 < 32; ++s2) s += ld_f(qb + (size_t)s2 * NN);
      wc = fmaf(REGL, Rcol[tid], s);
    }

    // 6. block-local updates: q = w + beta q; p = r + beta p;
    //    x += alpha p; r -= alpha q.
    {
      float qn = fmaf(beta, Qrow[tid], wr);
      Qrow[tid] = qn;
      Rrow[tid] = fmaf(-alpha, qn, Rrow[tid]);
    }
    if (tid < 256) {
      float qn = fmaf(beta, Qcol[tid], wc);
      Qcol[tid] = qn;
      float pn = fmaf(beta, Pcol[tid], Rcol[tid]);
      Pcol[tid] = pn;
      Xcol[tid] = fmaf(alpha, pn, Xcol[tid]);
      Rcol[tid] = fmaf(-alpha, qn, Rcol[tid]);
    }
    if (!db) gbarrier(bar);  // single-buffer: protect qp before next matvec
    // db=1: cross-thread Rrow reads next iter are covered by the loop-top
    // __syncthreads(); qp reuse is protected by the alternating buffer.
  }

  // ---- predict: out = K_test @ x, x = Xcol (block-local) ----
  {
    v8s th[4], tl[4];
#pragma unroll
    for (int rs = 0; rs < 4; ++rs)
      conv_frag(Xte, i0 + rs * 16 + n, q4 * 8, th[rs], tl[rs]);
    if (tid < 256) Wj[tid] = Xcol[tid] * Ebj[tid];
    Erow[tid] = fast_exp2(xx_te[rowbase + tid]);
    __syncthreads();
    float racc[4][4] = {};
    mv_compute(th, tl, Bh, Bl, Wj, lane, racc);
#pragma unroll
    for (int rs = 0; rs < 4; ++rs)
#pragma unroll
      for (int u = 0; u < 4; ++u) {
#pragma unroll
        for (int m = 1; m < 16; m <<= 1)
          racc[rs][u] += __shfl_xor(racc[rs][u], m, 64);
      }
    if (n == 0) {
#pragma unroll
      for (int rs = 0; rs < 4; ++rs)
#pragma unroll
        for (int u = 0; u < 4; ++u) {
          int lrow = wid * 64 + rs * 16 + q4 * 4 + u;
          st_f(&qp0[(size_t)sli * NN + rowbase + lrow],
               racc[rs][u] * Erow[lrow]);
        }
    }
    gbarrier(bar);
    if (sli == 0) {
      const float* qb = qp0 + rowbase + tid;
      float s = 0.f;
#pragma unroll
      for (int s2 = 0; s2 < 32; ++s2) s += ld_f(qb + (size_t)s2 * NN);
      out[rowbase + tid] = s;
    }
  }
}

// ---------------- launcher ----------------

extern "C" void kernel_launch(void* const* d_in, const int* in_sizes, int n_in,
                              void* d_out, int out_size, void* d_ws,
                              size_t ws_size, hipStream_t stream) {
  const float* X_train = (const float*)d_in[0];
  const float* y_train = (const float*)d_in[1];
  const float* X_test = (const float*)d_in[2];
  float* out = (float*)d_out;

  char* w = (char*)d_ws;
  size_t off = 0;
  float* xx_tr = (float*)(w + off); off += NN * 4;
  float* xx_te = (float*)(w + off); off += NN * 4;
  double* rho_s = (double*)(w + off); off += (size_t)NITER * 32 * 8;
  double* mu_s = (double*)(w + off); off += (size_t)NITER * 32 * 8;
  unsigned* bar = (unsigned*)(w + off); off += 2048;
  off = (off + 255) & ~(size_t)255;
  float* qp0 = (float*)(w + off); off += (size_t)32 * NN * 4;  // 1MB
  size_t need0 = off;
  float* qp1 = (float*)(w + off); off += (size_t)32 * NN * 4;  // 1MB
  size_t need1 = off;

  int db = (ws_size >= need1) ? 1 : 0;
  if (ws_size < need0) return;  // ~1.2MB; proven available (R12/R13 ran)
  if (!db) qp1 = qp0;

  const int nslots = 2 * NITER * 32;
  setup_zero<<<32, 256, 0, stream>>>(rho_s, nslots, bar);
  row_norms<<<NN / 256, 256, 0, stream>>>(X_train, xx_tr);
  row_norms<<<NN / 256, 256, 0, stream>>>(X_test, xx_te);

  cg_persist<<<NBLK, 1024, 0, stream>>>(X_train, X_test, xx_tr, xx_te,
                                        y_train, qp0, qp1, rho_s, mu_s, bar,
                                        out, db);
}

// Round 16
// 2115.979 us; speedup vs baseline: 1.3727x; 1.1359x over previous
//
#include <hip/hip_runtime.h>

// Kernel ridge regression, RBF kernel. N=M=8192, D=32, gamma=1/32, reg=1e-3.
// R16 = R15 (single-barrier Chronopoulos-Gear CG, block-local LDS vectors,
// fence-free relaxed agent-scope atomics) +
//  1) mu/rho slot ATOMICS -> plain per-block STORES (mu: 256 slots/iter, one
//     per block; rho: 8 line-padded slots/iter) with post-barrier parallel
//     reduce by wave 0 (4 coalesced loads/lane + butterfly). Removes the
//     ~3us pre-barrier RMW serialization tail (256 adds over 32 slots was
//     8-way ~900cy serialized).
//  2) NITER 112 -> 104: bounded by err(80)=0.0703 (fail), err(112)<=0.0156;
//     log-interp err(104)~0.023, ~2.8x margin under 0.0644 threshold.

#define NN 8192
#define DD 32
#define REGL 1e-3f
#define NITER 104
#define NBLK 256
#define NC2 (-0.045084220027780106f)  // -gamma*log2e
#define SCF (0.3002806023f)           // sqrt(2*gamma*log2e)

typedef short v8s __attribute__((ext_vector_type(8)));
typedef float v4f __attribute__((ext_vector_type(4)));

__device__ __forceinline__ float fast_exp2(float x) {
#if __has_builtin(__builtin_amdgcn_exp2f)
  return __builtin_amdgcn_exp2f(x);
#else
  float r;
  asm("v_exp_f32 %0, %1" : "=v"(r) : "v"(x));
  return r;
#endif
}

// ---- relaxed agent-scope coherent accessors ----
__device__ __forceinline__ float ld_f(const float* p) {
  return __hip_atomic_load(p, __ATOMIC_RELAXED, __HIP_MEMORY_SCOPE_AGENT);
}
__device__ __forceinline__ void st_f(float* p, float v) {
  __hip_atomic_store(p, v, __ATOMIC_RELAXED, __HIP_MEMORY_SCOPE_AGENT);
}
__device__ __forceinline__ double ld_d(const double* p) {
  return __hip_atomic_load(p, __ATOMIC_RELAXED, __HIP_MEMORY_SCOPE_AGENT);
}
__device__ __forceinline__ void st_d(double* p, double v) {
  __hip_atomic_store(p, v, __ATOMIC_RELAXED, __HIP_MEMORY_SCOPE_AGENT);
}

__device__ __forceinline__ ushort f2bf(float x) {  // RNE float->bf16 bits
  unsigned u = __float_as_uint(x);
  return (ushort)((u + 0x7fff + ((u >> 16) & 1)) >> 16);
}
__device__ __forceinline__ float bf2f(ushort b) {
  return __uint_as_float(((unsigned)b) << 16);
}

__device__ __forceinline__ double bfly64_d(double v) {
#pragma unroll
  for (int m = 1; m < 64; m <<= 1) v += __shfl_xor(v, m, 64);
  return v;
}
__device__ __forceinline__ double wave_down_sum_d(double v) {
#pragma unroll
  for (int off = 32; off > 0; off >>= 1) v += __shfl_down(v, off, 64);
  return v;
}

// ---- fence-free hierarchical global barrier (validated R11-R15) ----
__device__ __forceinline__ void gbarrier(unsigned* bar) {
  __builtin_amdgcn_s_waitcnt(0);
  __syncthreads();
  if (threadIdx.x == 0) {
    unsigned* gen = bar + 272;
    unsigned g =
        __hip_atomic_load(gen, __ATOMIC_RELAXED, __HIP_MEMORY_SCOPE_AGENT);
    unsigned a = __hip_atomic_fetch_add(&bar[(blockIdx.x >> 4) * 16], 1u,
                                        __ATOMIC_RELAXED,
                                        __HIP_MEMORY_SCOPE_AGENT);
    bool pub = false;
    if (a == 15u) {
      unsigned ra = __hip_atomic_fetch_add(bar + 256, 1u, __ATOMIC_RELAXED,
                                           __HIP_MEMORY_SCOPE_AGENT);
      if (ra == 15u) {
#pragma unroll
        for (int k = 0; k < 16; ++k)
          __hip_atomic_store(&bar[k * 16], 0u, __ATOMIC_RELAXED,
                             __HIP_MEMORY_SCOPE_AGENT);
        __hip_atomic_store(bar + 256, 0u, __ATOMIC_RELAXED,
                           __HIP_MEMORY_SCOPE_AGENT);
        __builtin_amdgcn_s_waitcnt(0);
        __hip_atomic_store(gen, g + 1u, __ATOMIC_RELAXED,
                           __HIP_MEMORY_SCOPE_AGENT);
        pub = true;
      }
    }
    if (!pub) {
      unsigned t = 0;
      while (__hip_atomic_load(gen, __ATOMIC_RELAXED,
                               __HIP_MEMORY_SCOPE_AGENT) == g) {
        if (t < 64)
          __builtin_amdgcn_s_sleep(1);
        else
          __builtin_amdgcn_s_sleep(8);
        if (++t > (1u << 20)) break;  // escape hatch: fail, don't hang
      }
    }
  }
  __atomic_signal_fence(__ATOMIC_SEQ_CST);
  __syncthreads();
}

// hi/lo bf16 fragment from global X: lane holds row `row`, k = kb..kb+7.
__device__ __forceinline__ void conv_frag(const float* __restrict__ X, int row,
                                          int kb, v8s& h, v8s& l) {
  const float4* rp = (const float4*)(X + (size_t)row * DD + kb);
  float4 f0 = rp[0], f1 = rp[1];
  float f[8] = {f0.x, f0.y, f0.z, f0.w, f1.x, f1.y, f1.z, f1.w};
  union {
    v8s v;
    ushort u[8];
  } H, L;
#pragma unroll
  for (int j = 0; j < 8; ++j) {
    float fs = SCF * f[j];
    ushort hb = f2bf(fs);
    H.u[j] = hb;
    L.u[j] = f2bf(fs - bf2f(hb));
  }
  h = H.v;
  l = L.v;
}

// ---------------- setup kernels ----------------

__global__ void setup_zero(unsigned* __restrict__ bar) {
  int i = blockIdx.x * 256 + threadIdx.x;
  if (i < 512) bar[i] = 0u;
}

// stores NC2 * ||x||^2
__global__ void row_norms(const float* __restrict__ X, float* __restrict__ xx) {
  int i = blockIdx.x * blockDim.x + threadIdx.x;
  if (i < NN) {
    const float4* row = (const float4*)(X + (size_t)i * DD);
    float s = 0.f;
#pragma unroll
    for (int k = 0; k < DD / 4; ++k) {
      float4 v = row[k];
      s += v.x * v.x + v.y * v.y + v.z * v.z + v.w * v.w;
    }
    xx[i] = NC2 * s;
  }
}

// ---------------- matvec compute core (4 row-tiles / wave) ----------------
__device__ __forceinline__ void mv_compute(const v8s* ah, const v8s* al,
                                           const ushort (*Bh)[512],
                                           const ushort (*Bl)[512],
                                           const float* Wj, int lane,
                                           float racc[4][4]) {
  const int n = lane & 15;
  for (int t = 0; t < 16; ++t) {
    v8s bh = *(const v8s*)&Bh[t][lane * 8];
    v8s bl = *(const v8s*)&Bl[t][lane * 8];
    float wn = Wj[t * 16 + n];
#pragma unroll
    for (int rs = 0; rs < 4; ++rs) {
      v4f c = {0.f, 0.f, 0.f, 0.f};
      c = __builtin_amdgcn_mfma_f32_16x16x32_bf16(al[rs], bh, c, 0, 0, 0);
      c = __builtin_amdgcn_mfma_f32_16x16x32_bf16(ah[rs], bl, c, 0, 0, 0);
      c = __builtin_amdgcn_mfma_f32_16x16x32_bf16(ah[rs], bh, c, 0, 0, 0);
#pragma unroll
      for (int u = 0; u < 4; ++u)
        racc[rs][u] = fmaf(fast_exp2(c[u]), wn, racc[rs][u]);
    }
  }
}

// ---------------- persistent CG-CG kernel ----------------
// Grid 256 blocks x 1024 threads: 8 rowblocks (1024 rows) x 32 slices
// (256 cols). All CG vectors live in block-local LDS.

__global__ __launch_bounds__(1024, 4) void cg_persist(
    const float* __restrict__ Xtr, const float* __restrict__ Xte,
    const float* __restrict__ xx_tr, const float* __restrict__ xx_te,
    const float* __restrict__ y, float* __restrict__ qp0,
    float* __restrict__ qp1, double* __restrict__ rho_s,
    double* __restrict__ mu_s, unsigned* __restrict__ bar,
    float* __restrict__ out, int db) {
  __shared__ __align__(16) ushort Bh[16][512];
  __shared__ __align__(16) ushort Bl[16][512];
  __shared__ float Wj[256];
  __shared__ float Ebj[256];
  __shared__ float Erow[1024];
  __shared__ float Rrow[1024], Qrow[1024];
  __shared__ float Rcol[256], Qcol[256], Pcol[256], Xcol[256];
  __shared__ double sredq[16];
  __shared__ double sredr[16];
  __shared__ float s_ab[2];  // alpha, beta

  const int tid = threadIdx.x;
  const int lane = tid & 63;
  const int wid = tid >> 6;
  const int n = lane & 15, q4 = lane >> 4;
  const int rbi = blockIdx.x & 7;
  const int sli = blockIdx.x >> 3;
  const int rowbase = rbi * 1024;
  const int i0 = rowbase + wid * 64;
  const int jbase = sli * 256;

  // ---- stage B-slice into LDS once ----
  {
    int c = tid & 255;
    int j = jbase + c;
    int g = tid >> 8;
    int tile = c >> 4, cl = c & 15;
    const float4* rp = (const float4*)(Xtr + (size_t)j * DD);
    float4 f0 = rp[2 * g], f1 = rp[2 * g + 1];
    float f[8] = {f0.x, f0.y, f0.z, f0.w, f1.x, f1.y, f1.z, f1.w};
    union {
      ushort u[8];
      uint4 qq;
    } H, L;
#pragma unroll
    for (int e = 0; e < 8; ++e) {
      float fs = SCF * f[e];
      ushort hb = f2bf(fs);
      H.u[e] = hb;
      L.u[e] = f2bf(fs - bf2f(hb));
    }
    int ln = cl + 16 * g;
    *(uint4*)&Bh[tile][ln * 8] = H.qq;
    *(uint4*)&Bl[tile][ln * 8] = L.qq;
  }
  if (tid < 256) Ebj[tid] = fast_exp2(xx_tr[jbase + tid]);
  Erow[tid] = fast_exp2(xx_tr[rowbase + tid]);

  // ---- block-local CG state ----
  Rrow[tid] = y[rowbase + tid];
  Qrow[tid] = 0.f;
  if (tid < 256) {
    Rcol[tid] = y[jbase + tid];
    Qcol[tid] = 0.f;
    Pcol[tid] = 0.f;
    Xcol[tid] = 0.f;
  }

  // ---- A fragments in registers, converted once ----
  v8s ah[4], al[4];
#pragma unroll
  for (int rs = 0; rs < 4; ++rs)
    conv_frag(Xtr, i0 + rs * 16 + n, q4 * 8, ah[rs], al[rs]);

  double rho_old = 1.0, alpha_old = 1.0;  // wave-0 recurrence state
  __syncthreads();

  for (int it = 0; it < NITER; ++it) {
    float* qp = (db && (it & 1)) ? qp1 : qp0;

    // 1. matvec input: Wj = r_k[cols] * col exp factor
    if (tid < 256) Wj[tid] = Rcol[tid] * Ebj[tid];
    // 2. rho partial (slice-0 blocks): r.r over this rowblock
    if (sli == 0) {
      float rvv = Rrow[tid];
      double acc = wave_down_sum_d((double)rvv * (double)rvv);
      if (lane == 0) sredr[wid] = acc;
    }
    __syncthreads();
    if (sli == 0 && tid == 0) {
      double t = 0.0;
#pragma unroll
      for (int k3 = 0; k3 < 16; ++k3) t += sredr[k3];
      st_d(&rho_s[(size_t)it * 128 + rbi * 16], t);  // plain store, own line
    }

    // 3. matvec on r
    float racc[4][4] = {};
    mv_compute(ah, al, Bh, Bl, Wj, lane, racc);
#pragma unroll
    for (int rs = 0; rs < 4; ++rs)
#pragma unroll
      for (int u = 0; u < 4; ++u) {
#pragma unroll
        for (int m = 1; m < 16; m <<= 1)
          racc[rs][u] += __shfl_xor(racc[rs][u], m, 64);
      }
    double cmu = 0.0;
    if (n == 0) {
#pragma unroll
      for (int rs = 0; rs < 4; ++rs)
#pragma unroll
        for (int u = 0; u < 4; ++u) {
          int lrow = wid * 64 + rs * 16 + q4 * 4 + u;
          float qc = racc[rs][u] * Erow[lrow];  // (K r)_row, this slice
          st_f(&qp[(size_t)sli * NN + rowbase + lrow], qc);
          cmu += (double)qc * (double)Rrow[lrow];  // r.Kr partial
        }
    }
    cmu = bfly64_d(cmu);
    if (lane == 0) sredq[wid] = cmu;
    __syncthreads();
    if (tid == 0) {
      double t = 0.0;
#pragma unroll
      for (int k3 = 0; k3 < 16; ++k3) t += sredq[k3];
      st_d(&mu_s[(size_t)it * 256 + blockIdx.x], t);  // own slot, no RMW
    }

    gbarrier(bar);  // the ONE barrier: qp + rho + mu complete

    // 4. scalars via CG-CG recurrence (wave 0, then LDS broadcast);
    //    mu: 256 per-block slots reduced with 4 coalesced loads/lane.
    if (wid == 0) {
      const double* mb = mu_s + (size_t)it * 256;
      double m = ld_d(mb + lane) + ld_d(mb + lane + 64) +
                 ld_d(mb + lane + 128) + ld_d(mb + lane + 192);
      double rv_l =
          (lane < 8) ? ld_d(rho_s + (size_t)it * 128 + lane * 16) : 0.0;
      double m1 = bfly64_d(m);
      double r1 = bfly64_d(rv_l);
      double mu = m1 + (double)REGL * r1;  // r.(K+reg I)r
      double beta_d = (it == 0) ? 0.0 : r1 / rho_old;
      double alpha_d =
          (it == 0) ? r1 / mu : r1 / (mu - r1 * beta_d / alpha_old);
      rho_old = r1;
      alpha_old = alpha_d;
      if (lane == 0) {
        s_ab[0] = (float)alpha_d;
        s_ab[1] = (float)beta_d;
      }
    }
    __syncthreads();
    const float alpha = s_ab[0], beta = s_ab[1];

    // 5. gather w = K r (+reg r) at rows and cols; flat ascending slice
    //    order everywhere so replicated values stay bitwise identical.
    float wr;
    {
      const float* qb = qp + rowbase + tid;
      float s = 0.f;
#pragma unroll
      for (int s2 = 0; s2 < 32; ++s2) s += ld_f(qb + (size_t)s2 * NN);
      wr = fmaf(REGL, Rrow[tid], s);
    }
    float wc = 0.f;
    if (tid < 256) {
      const float* qb = qp + jbase + tid;
      float s = 0.f;
#pragma unroll
      for (int s2 = 0; s2 < 32; ++s2) s += ld_f(qb + (size_t)s2 * NN);
      wc = fmaf(REGL, Rcol[tid], s);
    }

    // 6. block-local updates: q = w + beta q; p = r + beta p;
    //    x += alpha p; r -= alpha q.
    {
      float qn = fmaf(beta, Qrow[tid], wr);
      Qrow[tid] = qn;
      Rrow[tid] = fmaf(-alpha, qn, Rrow[tid]);
    }
    if (tid < 256) {
      float qn = fmaf(beta, Qcol[tid], wc);
      Qcol[tid] = qn;
      float pn = fmaf(beta, Pcol[tid], Rcol[tid]);
      Pcol[tid] = pn;
      Xcol[tid] = fmaf(alpha, pn, Xcol[tid]);
      Rcol[tid] = fmaf(-alpha, qn, Rcol[tid]);
    }
    if (!db) gbarrier(bar);  // single-buffer: protect qp before next matvec
    // db=1: cross-thread Rrow reads next iter are covered by the loop-top
    // __syncthreads(); qp reuse is protected by the alternating buffer.
  }

  // ---- predict: out = K_test @ x, x = Xcol (block-local) ----
  {
    v8s th[4], tl[4];
#pragma unroll
    for (int rs = 0; rs < 4; ++rs)
      conv_frag(Xte, i0 + rs * 16 + n, q4 * 8, th[rs], tl[rs]);
    if (tid < 256) Wj[tid] = Xcol[tid] * Ebj[tid];
    Erow[tid] = fast_exp2(xx_te[rowbase + tid]);
    __syncthreads();
    float racc[4][4] = {};
    mv_compute(th, tl, Bh, Bl, Wj, lane, racc);
#pragma unroll
    for (int rs = 0; rs < 4; ++rs)
#pragma unroll
      for (int u = 0; u < 4; ++u) {
#pragma unroll
        for (int m = 1; m < 16; m <<= 1)
          racc[rs][u] += __shfl_xor(racc[rs][u], m, 64);
      }
    if (n == 0) {
#pragma unroll
      for (int rs = 0; rs < 4; ++rs)
#pragma unroll
        for (int u = 0; u < 4; ++u) {
          int lrow = wid * 64 + rs * 16 + q4 * 4 + u;
          st_f(&qp0[(size_t)sli * NN + rowbase + lrow],
               racc[rs][u] * Erow[lrow]);
        }
    }
    gbarrier(bar);
    if (sli == 0) {
      const float* qb = qp0 + rowbase + tid;
      float s = 0.f;
#pragma unroll
      for (int s2 = 0; s2 < 32; ++s2) s += ld_f(qb + (size_t)s2 * NN);
      out[rowbase + tid] = s;
    }
  }
}

// ---------------- launcher ----------------

extern "C" void kernel_launch(void* const* d_in, const int* in_sizes, int n_in,
                              void* d_out, int out_size, void* d_ws,
                              size_t ws_size, hipStream_t stream) {
  const float* X_train = (const float*)d_in[0];
  const float* y_train = (const float*)d_in[1];
  const float* X_test = (const float*)d_in[2];
  float* out = (float*)d_out;

  char* w = (char*)d_ws;
  size_t off = 0;
  float* xx_tr = (float*)(w + off); off += NN * 4;
  float* xx_te = (float*)(w + off); off += NN * 4;
  double* rho_s = (double*)(w + off); off += (size_t)NITER * 128 * 8;
  double* mu_s = (double*)(w + off); off += (size_t)NITER * 256 * 8;
  unsigned* bar = (unsigned*)(w + off); off += 2048;
  off = (off + 255) & ~(size_t)255;
  float* qp0 = (float*)(w + off); off += (size_t)32 * NN * 4;  // 1MB
  size_t need0 = off;
  float* qp1 = (float*)(w + off); off += (size_t)32 * NN * 4;  // 1MB
  size_t need1 = off;

  int db = (ws_size >= need1) ? 1 : 0;
  if (ws_size < need0) return;  // ~1.5MB; ws >= ~2.3MB proven (R13-R15 db)
  if (!db) qp1 = qp0;

  setup_zero<<<2, 256, 0, stream>>>(bar);
  row_norms<<<NN / 256, 256, 0, stream>>>(X_train, xx_tr);
  row_norms<<<NN / 256, 256, 0, stream>>>(X_test, xx_te);

  cg_persist<<<NBLK, 1024, 0, stream>>>(X_train, X_test, xx_tr, xx_te,
                                        y_train, qp0, qp1, rho_s, mu_s, bar,
                                        out, db);
}